// Round 13
// baseline (1019.155 us; speedup 1.0000x reference)
//
#include <hip/hip_runtime.h>
#include <math.h>

#define TT 512
#define VV 32000
#define NB 250          // blocks; 250*128 = 32000 columns
#define NTHR 512        // 8 waves
#define BCOLS 128
#define MAXIT 1000
#define CHK 50
#define NCHK (MAXIT / CHK)
#define FPSCALE 1024.0f // fixed-point scale for row-partial quantization
#define WPR 2           // sub-accumulator words per row (blocks split by b&1)
#define LSTR32 32       // u32 stride per data word = 128 B line isolation
#define ELSTR 32        // u32 stride for epoch counters / ready flags
#define LDS_BYTES 136576

typedef float f4 __attribute__((ext_vector_type(4)));
typedef _Float16 h8 __attribute__((ext_vector_type(8)));
typedef _Float16 h2 __attribute__((ext_vector_type(2)));
typedef unsigned long long u64;
typedef unsigned u32;

// ---- DPP wave reductions ----
template <int CTRL>
__device__ __forceinline__ float dpp_add(float x) {
  int y = __builtin_amdgcn_update_dpp(0, __builtin_bit_cast(int, x), CTRL, 0xF, 0xF, true);
  return x + __builtin_bit_cast(float, y);
}
__device__ __forceinline__ float red16(float x) {  // valid on lanes 15 mod 16
  x = dpp_add<0x111>(x); x = dpp_add<0x112>(x);
  x = dpp_add<0x114>(x); x = dpp_add<0x118>(x);
  return x;
}
__device__ __forceinline__ float red32(float x) {  // valid on lanes 31, 63
  x = red16(x); x = dpp_add<0x142>(x); return x;
}
__device__ __forceinline__ float red64(float x) {  // valid on lane 63
  x = red32(x); x = dpp_add<0x143>(x); return x;
}

__device__ __forceinline__ int fswz(int row) { return (row ^ (row >> 5)) & 15; }

__device__ __forceinline__ u32 ald32(const u32* p) {
  return __hip_atomic_load(p, __ATOMIC_RELAXED, __HIP_MEMORY_SCOPE_AGENT);
}
__device__ __forceinline__ float aldf(const float* p) {
  return __hip_atomic_load(p, __ATOMIC_RELAXED, __HIP_MEMORY_SCOPE_AGENT);
}

// Burst-read the (immutable) data words for this parity; cumulative modular
// deltas vs per-lane prev arrays. PHA/PHB: NAMED arrays, compile-time j
// indices only (rule #20). Flags already confirmed completeness — no loop.
#define READ_U(PHA, PHB, DQ)                                                   \
  {                                                                            \
    u32 va[8], vb[8];                                                          \
    _Pragma("unroll")                                                          \
    for (int j = 0; j < 8; ++j) {                                              \
      va[j] = ald32(&(DQ)[(size_t)((64 * j + t) * WPR + 0) * LSTR32]);         \
      vb[j] = ald32(&(DQ)[(size_t)((64 * j + t) * WPR + 1) * LSTR32]);         \
    }                                                                          \
    _Pragma("unroll")                                                          \
    for (int j = 0; j < 8; ++j) {                                              \
      u32 dlt = (va[j] - (PHA)[j]) + (vb[j] - (PHB)[j]);                       \
      (PHA)[j] = va[j]; (PHB)[j] = vb[j];                                      \
      float Dv = (float)dlt * (1.0f / FPSCALE);                                \
      uf[64 * j + t] = 1.f / (Dv * (1.f / VV) + 1e-16f);                       \
    }                                                                          \
  }

extern "C" __global__ void __launch_bounds__(NTHR, 1)
sink_kernel(const float* __restrict__ cost, u32* __restrict__ Dsum,
            u32* __restrict__ ecnt, u32* __restrict__ rdy,
            float* __restrict__ errb, float* __restrict__ lossp) {
  extern __shared__ char smem[];
  h8*       tile8  = (h8*)smem;                      // 512 x 16 chunks (swizzled), 128 KB
  float*    uf     = (float*)(smem + 131072);        // 512 f32
  float*    u_prev = (float*)(smem + 133120);        // 512 f32
  float*    vf     = (float*)(smem + 135168);        // 128 f32
  float*    v_prev = (float*)(smem + 135680);        // 128 f32
  _Float16* vh     = (_Float16*)(smem + 136192);     // 128 f16
  h8*       vh8    = (h8*)vh;
  float*    errw   = (float*)(smem + 136448);        // 16 f32
  float*    wred   = (float*)(smem + 136512);        // 8 f32
  int*      jflag  = (int*)(smem + 136544);          // 8 i32 (u-ready flag in [0])

  const int t  = threadIdx.x;
  const int b  = blockIdx.x;
  const int cB = t & 15;        // chunk (8 cols)   — row-wise map (Phase B)
  const int rB = t >> 4;        // row slice 0..31
  const int gA = t >> 5;        // col-chunk        — Phase A map
  const int sA = t & 31;        // row-within-chunk 0..31
  const int ln = t & 63;

  const float* cb = cost + (size_t)b * BCOLS;

  // ---- load tile: K~ = fp16(exp(-20 c)) ----
  for (int i = 0; i < 16; ++i) {
    int row = rB + 32 * i;
    const float* p = cb + (size_t)row * VV + cB * 8;
    f4 x0 = *(const f4*)p;
    f4 x1 = *(const f4*)(p + 4);
    h8 kk;
#pragma unroll
    for (int e = 0; e < 4; ++e) kk[e]     = (_Float16)__expf(-20.f * x0[e]);
#pragma unroll
    for (int e = 0; e < 4; ++e) kk[4 + e] = (_Float16)__expf(-20.f * x1[e]);
    tile8[row * 16 + (cB ^ fswz(row))] = kk;
  }
  uf[t] = 1.0f;  // u_bar_0 = 1
  if (t < 8) jflag[t] = 0;
  __syncthreads();

  const bool writerA = ((t & 31) == 31);
  bool converged = false;
  u32 ph0a[8], ph0b[8], ph1a[8], ph1b[8];  // per-lane prev data words (wave 0)
#pragma unroll
  for (int j = 0; j < 8; ++j) { ph0a[j] = 0u; ph0b[j] = 0u; ph1a[j] = 0u; ph1b[j] = 0u; }

  for (int it = 0; it < MAXIT; ++it) {
    const bool chkc = (it > 0) && (it % CHK == 0);
    const bool pending = ((it % CHK) == 1) && (it > CHK);
    const int ciW = it / CHK - 1;
    const int ciR = (it - 1) / CHK - 1;

    if (pending) { u_prev[t] = uf[t]; __syncthreads(); }

    // ---- u acquire: wave 0 polls 8 quiet flag lines, then burst-reads data ----
    if (t < 64) {
      if (it > 0) {
        const u32 need = (u32)it;  // completion stamp of iter it-1
        for (;;) {
          u32 fv = __hip_atomic_load(&rdy[(t & 7) * ELSTR], __ATOMIC_ACQUIRE,
                                     __HIP_MEMORY_SCOPE_AGENT);
          if (__all(fv >= need)) break;
          __builtin_amdgcn_s_sleep(1);
        }
        const u32* Dprev = Dsum + (size_t)((it - 1) & 1) * TT * WPR * LSTR32;
        if (((it - 1) & 1) == 0) { READ_U(ph0a, ph0b, Dprev) }
        else                     { READ_U(ph1a, ph1b, Dprev) }
        asm volatile("s_waitcnt lgkmcnt(0)" ::: "memory");
      }
      if (t == 0)
        __hip_atomic_store(&jflag[0], (int)(it + 1), __ATOMIC_RELEASE,
                           __HIP_MEMORY_SCOPE_WORKGROUP);
    }

    // ---- all waves: wait u-ready (cross-wave LDS spin: safe), decide, compute ----
    while (__hip_atomic_load(&jflag[0], __ATOMIC_ACQUIRE,
                             __HIP_MEMORY_SCOPE_WORKGROUP) != (int)(it + 1))
      __builtin_amdgcn_s_sleep(1);
    if (pending) {
      u32 eb = 0;
      if (ln == 0) eb = __builtin_bit_cast(u32, aldf(&errb[ciR]));
      eb = __builtin_amdgcn_readfirstlane(eb);
      if (__builtin_bit_cast(float, eb) < 0.005f * VV) { converged = true; break; }
    }

    // ---- Phase A: acc_j = sum_rows K~ * u_bar ----
    float acc[8];
#pragma unroll
    for (int e = 0; e < 8; ++e) acc[e] = 0.f;
#pragma unroll
    for (int i = 0; i < 16; ++i) {
      int row = 32 * i + sA;
      h8 kk = tile8[row * 16 + (gA ^ fswz(row))];
      float uu = uf[row];
#pragma unroll
      for (int e = 0; e < 8; ++e) acc[e] = fmaf((float)kk[e], uu, acc[e]);
    }
#pragma unroll
    for (int e = 0; e < 8; ++e) acc[e] = red32(acc[e]);

    // ---- v_bar = 1/(Sa + 1e-16); err uses OLD v ----
    if (writerA) {
      float el = 0.f;
#pragma unroll
      for (int e = 0; e < 8; ++e) {
        float sa = acc[e] * (1.f / TT);
        float vo = vf[gA * 8 + e];
        if (chkc) { el += fabsf(vo * sa - 1.f); v_prev[gA * 8 + e] = vo; }
        float nv = 1.f / (sa + 1e-16f);
        vf[gA * 8 + e] = nv;
        vh[gA * 8 + e] = (_Float16)nv;
      }
      if (chkc) errw[gA] = el;
    }
    __syncthreads();
    if (chkc) {
      if (t == 0) {
        float s = 0.f;
#pragma unroll
        for (int w = 0; w < 16; ++w) s += errw[w];
        __hip_atomic_fetch_add(&errb[ciW], s, __ATOMIC_RELAXED, __HIP_MEMORY_SCOPE_AGENT);
      }
      __syncthreads();  // drain err add before any Dsum add of this iter
    }

    // ---- Phase B: value-only fixed-point atomics to private data lines ----
    u32* Dcur = Dsum + (size_t)(it & 1) * TT * WPR * LSTR32;
    const int sub = b & 1;
    h8 vv = vh8[cB];
    for (int i = 0; i < 16; ++i) {
      int row = rB + 32 * i;
      h8 kk = tile8[row * 16 + (cB ^ fswz(row))];
      float rs = 0.f;
      rs = __builtin_amdgcn_fdot2(h2{kk[0], kk[1]}, h2{vv[0], vv[1]}, rs, false);
      rs = __builtin_amdgcn_fdot2(h2{kk[2], kk[3]}, h2{vv[2], vv[3]}, rs, false);
      rs = __builtin_amdgcn_fdot2(h2{kk[4], kk[5]}, h2{vv[4], vv[5]}, rs, false);
      rs = __builtin_amdgcn_fdot2(h2{kk[6], kk[7]}, h2{vv[6], vv[7]}, rs, false);
      rs = red16(rs);
      if ((t & 15) == 15) {
        u32 qv = (u32)(int)__builtin_rintf(rs * FPSCALE);
        __hip_atomic_fetch_add(&Dcur[(size_t)(row * WPR + sub) * LSTR32], qv,
                               __ATOMIC_RELAXED, __HIP_MEMORY_SCOPE_AGENT);
      }
    }
    // ---- completion: ack data atomics, then epoch add (separate lines) ----
    asm volatile("s_waitcnt vmcnt(0)" ::: "memory");
    __syncthreads();
    if (t == 0)
      __hip_atomic_fetch_add(&ecnt[(size_t)(it & 1) * 8 * ELSTR + (b & 7) * ELSTR],
                             1u, __ATOMIC_RELEASE, __HIP_MEMORY_SCOPE_AGENT);
    // ---- detection: 8 leaders each poll own group counter, release rdy flag ----
    if (b < 8 && t == 0) {
      const u32 tgt = (b < 2 ? 32u : 31u) * (u32)((it >> 1) + 1);
      const u32* ec = &ecnt[(size_t)(it & 1) * 8 * ELSTR + b * ELSTR];
      while (__hip_atomic_load(ec, __ATOMIC_ACQUIRE, __HIP_MEMORY_SCOPE_AGENT) < tgt)
        __builtin_amdgcn_s_sleep(1);
      __hip_atomic_store(&rdy[b * ELSTR], (u32)(it + 1), __ATOMIC_RELEASE,
                         __HIP_MEMORY_SCOPE_AGENT);
    }
    // no trailing block barrier: next iter's flag poll is the cross-block fence
  }

  if (converged) {  // restore pre-check state (reference exit semantics)
    __syncthreads();  // quiesce wave0's uf writes before overwrite
    uf[t] = u_prev[t];
    if (t < 128) vf[t] = v_prev[t];
    __syncthreads();
  } else {
    // MAXIT path: drain u_1000 (parity of iter 999 = 1) into LDS
    if (t < 64) {
      for (;;) {
        u32 fv = __hip_atomic_load(&rdy[(t & 7) * ELSTR], __ATOMIC_ACQUIRE,
                                   __HIP_MEMORY_SCOPE_AGENT);
        if (__all(fv >= (u32)MAXIT)) break;
        __builtin_amdgcn_s_sleep(1);
      }
      const u32* Dprev = Dsum + (size_t)((MAXIT - 1) & 1) * TT * WPR * LSTR32;
      READ_U(ph1a, ph1b, Dprev)
    }
    __syncthreads();
  }

  // ---- loss partial: sum u_bar * exp(-20c) * v_bar * c over own stripe ----
  float lacc = 0.f;
  for (int i = 0; i < 16; ++i) {
    int row = rB + 32 * i;
    const float* p = cb + (size_t)row * VV + cB * 8;
    f4 x0 = *(const f4*)p;
    f4 x1 = *(const f4*)(p + 4);
    float um = uf[row];
    float inner = 0.f;
#pragma unroll
    for (int e = 0; e < 4; ++e) inner = fmaf(vf[cB * 8 + e] * __expf(-20.f * x0[e]), x0[e], inner);
#pragma unroll
    for (int e = 0; e < 4; ++e) inner = fmaf(vf[cB * 8 + 4 + e] * __expf(-20.f * x1[e]), x1[e], inner);
    lacc = fmaf(um, inner, lacc);
  }
  lacc = red64(lacc);
  if ((t & 63) == 63) wred[t >> 6] = lacc;
  __syncthreads();
  if (t == 0) {
    float s = 0.f;
#pragma unroll
    for (int w = 0; w < 8; ++w) s += wred[w];
    lossp[b] = s;
  }
}

extern "C" __global__ void prep_kernel(u64* zbuf, float* out) {
  int gid = threadIdx.x + blockIdx.x * 256;
  // zero Dsum (262144 B) + ecnt (2048 B) + rdy (1024 B) + errb (80 B) = 33162 u64
  for (int i = gid; i < 33162; i += gridDim.x * 256) zbuf[i] = 0ull;
  if (gid == 0) out[0] = 0.f;
}

extern "C" __global__ void final_kernel(const float* __restrict__ lossp, float* __restrict__ out) {
  int t = threadIdx.x;  // 64 threads, one wave
  float s = 0.f;
  for (int i = t; i < NB; i += 64) s += lossp[i];
  s = red64(s);
  if (t == 63) out[0] = s * (100.0f / ((float)TT * (float)VV));
}

extern "C" void kernel_launch(void* const* d_in, const int* in_sizes, int n_in,
                              void* d_out, int out_size, void* d_ws, size_t ws_size,
                              hipStream_t stream) {
  const float* cost = (const float*)d_in[0];
  float* out = (float*)d_out;
  char* ws = (char*)d_ws;
  u32*   Dsum  = (u32*)ws;                  // 2*512*2*32 u32 = 262144 B
  u32*   ecnt  = (u32*)(ws + 262144);       // 2*8*32 u32 = 2048 B
  u32*   rdy   = (u32*)(ws + 264192);       // 8*32 u32 = 1024 B
  float* errb  = (float*)(ws + 265216);     // 20 f32 (80 B)
  float* lossp = (float*)(ws + 265344);     // 250 f32

  prep_kernel<<<130, 256, 0, stream>>>((u64*)ws, out);

  (void)hipFuncSetAttribute((const void*)sink_kernel,
                            hipFuncAttributeMaxDynamicSharedMemorySize, LDS_BYTES);
  void* args[] = {(void*)&cost, (void*)&Dsum, (void*)&ecnt, (void*)&rdy,
                  (void*)&errb, (void*)&lossp};
  (void)hipLaunchCooperativeKernel((const void*)sink_kernel, dim3(NB), dim3(NTHR),
                                   args, LDS_BYTES, stream);

  final_kernel<<<1, 64, 0, stream>>>(lossp, out);
}